// Round 4
// baseline (270.372 us; speedup 1.0000x reference)
//
#include <hip/hip_runtime.h>

#define DIM 1024
#define BLANK_ID 100
#define BATCH 4
#define SEQ 4096
#define ROWS_PER_BLOCK 8   // 16384 rows / 8 = 2048 blocks = 8 blocks/CU

// Clang-native vector: accepted by __builtin_nontemporal_store (HIP float4 is not).
typedef float f4 __attribute__((ext_vector_type(4)));

// Block = 256 threads; each thread owns one float4 column slot (d = tid*4)
// and walks 8 consecutive rows (same batch: 8 divides 4096).
// Row pair (r0 even, r1 = r0+1) shares condition terms:
//   c1(r1) needs t1,t0 ; c2(r1)==c1(r0) ; c3(r1)==c2(r0).
__global__ __launch_bounds__(256) void BlankEmbedding_kernel(
    const int* __restrict__ x, const float* __restrict__ emb,
    float* __restrict__ out) {
  const int rowBase = blockIdx.x * ROWS_PER_BLOCK;
  const int d = threadIdx.x << 2;

#pragma unroll
  for (int i = 0; i < ROWS_PER_BLOCK; i += 2) {
    const int r0 = rowBase + i;
    const int r1 = r0 + 1;
    const int s0 = r0 & (SEQ - 1);

    // Block-uniform token loads (scalar), guarded at batch front.
    const int t0  = x[r0];
    const int t1  = x[r1];
    const int tm1 = (s0 >= 1) ? x[r0 - 1] : -1;
    const int tm2 = (s0 >= 2) ? x[r0 - 2] : -1;
    const int tm3 = (s0 >= 3) ? x[r0 - 3] : -1;

    // Main gathers issued first — two independent 1 KB loads in flight.
    f4 acc0 = *(const f4*)(emb + (size_t)t0 * DIM + d);
    f4 acc1 = *(const f4*)(emb + (size_t)t1 * DIM + d);

    const bool c1 = (s0 >= 1) && (t0  == BLANK_ID) && (tm1 != BLANK_ID);
    const bool c2 = (s0 >= 2) && (tm1 == BLANK_ID) && (tm2 != BLANK_ID);
    const bool c3 = (s0 >= 3) && (tm2 == BLANK_ID) && (tm3 != BLANK_ID);
    const bool d1 = (t1 == BLANK_ID) && (t0 != BLANK_ID);  // c1 of row1

    if (c1) acc0 += *(const f4*)(emb + (size_t)tm1 * DIM + d);
    if (c2) acc0 += *(const f4*)(emb + (size_t)tm2 * DIM + d);
    if (c3) acc0 += *(const f4*)(emb + (size_t)tm3 * DIM + d);

    if (d1) acc1 += *(const f4*)(emb + (size_t)t0  * DIM + d);
    if (c1) acc1 += *(const f4*)(emb + (size_t)tm1 * DIM + d);  // c2 of row1
    if (c2) acc1 += *(const f4*)(emb + (size_t)tm2 * DIM + d);  // c3 of row1

    // Streaming stores: out is written once, never re-read.
    __builtin_nontemporal_store(acc0, (f4*)(out + (size_t)r0 * DIM + d));
    __builtin_nontemporal_store(acc1, (f4*)(out + (size_t)r1 * DIM + d));
  }
}

extern "C" void kernel_launch(void* const* d_in, const int* in_sizes, int n_in,
                              void* d_out, int out_size, void* d_ws, size_t ws_size,
                              hipStream_t stream) {
  const int*   x   = (const int*)d_in[0];     // [B, S] tokens (int32)
  const float* emb = (const float*)d_in[1];   // [VOCAB, DIM] fp32
  float*       out = (float*)d_out;           // [B, S, DIM] fp32

  dim3 grid((BATCH * SEQ) / ROWS_PER_BLOCK);
  dim3 block(256);
  BlankEmbedding_kernel<<<grid, block, 0, stream>>>(x, emb, out);
}